// Round 6
// baseline (969.092 us; speedup 1.0000x reference)
//
#include <hip/hip_runtime.h>
#include <stdint.h>

// IndexFlatIP top-k: sims = Q[512,512] @ X[262144,512]^T, per-row top-10
// indices (desc, ties -> lower index). Output int32 [512,10].
//
// Round 6: bigger step. BM=256 x BN=128 x BK=64, 8 waves (4M x 2N), wave
// tile 64x64 -> 32 MFMA / 16 ds_read_b128 per wave-step, 64 steps/block
// (vs 256). A staged via global_load_lds from granule-ordered Qsw (f16 RTZ);
// B reg-staged from fp32 X with cvt_pkrtz, issue-early/write-late (T14).
// Double-buffered LDS, one __syncthreads per step. Fused per-row top-6 per
// 1024-col chunk; p2 pivot-filter + exact fp32 rescore (unchanged, verified).
#define B_Q   512
#define N_IDX 262144
#define D_DIM 512
#define TOPK  10
#define CAND  6

constexpr int BM = 256, BN = 128, BK = 64;
constexpr int CHUNKS = 256;          // candidate chunks (1024 cols each)
constexpr int NR = N_IDX / CHUNKS;   // 1024
constexpr int NT = NR / BN;          // 8
constexpr int KT = D_DIM / BK;       // 8
constexpr int ITERS = NT * KT;       // 64
constexpr int NCAND = CHUNKS * CAND; // 1536
constexpr int CS_STRIDE = 34;        // Cs row stride (f32): 2-way-free banks

typedef _Float16 half8 __attribute__((ext_vector_type(8)));
typedef float    f32x4 __attribute__((ext_vector_type(4)));

__device__ __forceinline__ unsigned int pk16(float a, float b)
{
    return __builtin_bit_cast(unsigned int, __builtin_amdgcn_cvt_pkrtz(a, b));
}

__device__ __forceinline__ void glds16(const void* g, char* lds)
{
    __builtin_amdgcn_global_load_lds(
        (const __attribute__((address_space(1))) void*)g,
        (__attribute__((address_space(3))) void*)lds, 16, 0, 0);
}

// ------------------------------------------------------------------ qprep --
// Q fp32 -> f16 RTZ granules for p1: granule(qt,kt,ks,row) = 8 f16 of
// Q[qt*256+row][kt*64+ks*8 ..+8], stored at uint4 index
// (qt*8+kt)*2048 + ks*256 + row.
__global__ __launch_bounds__(256)
void qprep(const float* __restrict__ Q, uint4* __restrict__ QswU4)
{
    const int n = blockIdx.x * 256 + threadIdx.x;   // 32768 granules
    const int qt = n >> 14, row = (n >> 6) & 255, kt = (n >> 3) & 7, ks = n & 7;
    const float4* src = reinterpret_cast<const float4*>(Q)
                        + ((qt * 256 + row) * 128 + kt * 16 + ks * 2);
    const float4 p0 = src[0], p1 = src[1];
    uint4 u;
    u.x = pk16(p0.x, p0.y);
    u.y = pk16(p0.z, p0.w);
    u.z = pk16(p1.x, p1.y);
    u.w = pk16(p1.z, p1.w);
    QswU4[(qt * 8 + kt) * 2048 + ks * 256 + row] = u;
}

// --------------------------------------------------------------------- p1 --
// Grid 512 (chunk = bx>>1, qt = bx&1), block 512 = 8 waves (wm 0..3, wn 0..1).
// LDS 130 KB: Ab0 @0 (32K), Ab1 @32K, Bb0 @64K (16K), Bb1 @80K, Cs @96K.
// A granule layout per buf: (ks*256 + row)*16B, ks=0..7. B: (ks*128 + col)*16B.
__global__ __launch_bounds__(512, 2)
void faiss_p1(const uint4* __restrict__ QswU4, const float* __restrict__ X,
              float* __restrict__ cand_v, int* __restrict__ cand_i)
{
    __shared__ __align__(16) char smem[133120];
    float* Cs = (float*)(smem + 98304);

    const int tid  = threadIdx.x;
    const int lane = tid & 63;
    const int w    = tid >> 6;
    const int wm   = w >> 1;       // 0..3
    const int wn   = w & 1;        // 0..1
    const int chunk = blockIdx.x >> 1;
    const int qt    = blockIdx.x & 1;
    const int row0  = qt * 256;

    const uint4* Abase = QswU4 + (size_t)qt * 8 * 2048;

    // B staging: thread -> (col = tid>>2, kq = tid&3): 16 f32 -> 16 f16.
    const int bcol = tid >> 2, bkq = tid & 3;
    const float* Xbase = X + (size_t)(chunk * NR + bcol) * D_DIM + bkq * 16;
    const int bD0 = ((bkq * 2) * 128 + bcol) * 16;   // granule ks=bkq*2
    const int bD1 = bD0 + 128 * 16;                  // granule ks=bkq*2+1

    // fragment byte offsets (k-octet ks = kk*4 + (lane>>4))
    int a_off[2][4], b_off[2][4];
#pragma unroll
    for (int kk = 0; kk < 2; ++kk) {
#pragma unroll
        for (int mi = 0; mi < 4; ++mi)
            a_off[kk][mi] = ((kk * 4 + (lane >> 4)) * 256 + wm * 64 + mi * 16 + (lane & 15)) * 16;
#pragma unroll
        for (int ni = 0; ni < 4; ++ni)
            b_off[kk][ni] = ((kk * 4 + (lane >> 4)) * 128 + wn * 64 + ni * 16 + (lane & 15)) * 16;
    }

    float topv[CAND]; int topi[CAND];
#pragma unroll
    for (int j = 0; j < CAND; ++j) { topv[j] = -3.0e38f; topi[j] = 0; }

    f32x4 acc[4][4];
#pragma unroll
    for (int mi = 0; mi < 4; ++mi)
#pragma unroll
        for (int ni = 0; ni < 4; ++ni) acc[mi][ni] = (f32x4)0.0f;

    float4 breg[4];

    auto issueB = [&](int j) {      // 4 dwordx4 -> breg (step j's B tile)
        const int nt2 = j >> 3, kt2 = j & 7;
        const float* p = Xbase + (size_t)nt2 * (BN * D_DIM) + kt2 * 64;
#pragma unroll
        for (int q = 0; q < 4; ++q)
            breg[q] = *reinterpret_cast<const float4*>(p + q * 4);
    };
    auto issueA = [&](int j) {      // 4 glds per wave -> Ab[j&1]
        const uint4* src = Abase + (j & 7) * 2048;
        char* dst = smem + (j & 1) * 32768;
#pragma unroll
        for (int i = 0; i < 4; ++i)
            glds16(src + w * 256 + i * 64 + lane, dst + (w * 256 + i * 64) * 16);
    };
    auto writeB = [&](int j) {      // cvt + 2x b128 -> Bb[j&1]
        char* bb = smem + 65536 + (j & 1) * 16384;
        uint4 u0, u1;
        u0.x = pk16(breg[0].x, breg[0].y); u0.y = pk16(breg[0].z, breg[0].w);
        u0.z = pk16(breg[1].x, breg[1].y); u0.w = pk16(breg[1].z, breg[1].w);
        u1.x = pk16(breg[2].x, breg[2].y); u1.y = pk16(breg[2].z, breg[2].w);
        u1.z = pk16(breg[3].x, breg[3].y); u1.w = pk16(breg[3].z, breg[3].w);
        *(uint4*)(bb + bD0) = u0;
        *(uint4*)(bb + bD1) = u1;
    };

    // prologue: fill buffers for step 0
    issueB(0);
    __builtin_amdgcn_sched_barrier(0);
    issueA(0);
    __builtin_amdgcn_sched_barrier(0);
    asm volatile("s_waitcnt vmcnt(4)" ::: "memory");
    writeB(0);
    asm volatile("s_waitcnt vmcnt(0)" ::: "memory");
    __syncthreads();

    for (int j = 0; j < ITERS; ++j) {
        // issue next step's staging first (latency slack = this whole step)
        if (j + 1 < ITERS) {
            issueB(j + 1);
            __builtin_amdgcn_sched_barrier(0);
            issueA(j + 1);
        }
        __builtin_amdgcn_sched_barrier(0);

        // compute(j) from buf j&1
        {
            const char* ab = smem + (j & 1) * 32768;
            const char* bb = smem + 65536 + (j & 1) * 16384;
#pragma unroll
            for (int kk = 0; kk < 2; ++kk) {
                half8 af[4], bf[4];
#pragma unroll
                for (int mi = 0; mi < 4; ++mi)
                    af[mi] = *reinterpret_cast<const half8*>(ab + a_off[kk][mi]);
#pragma unroll
                for (int ni = 0; ni < 4; ++ni)
                    bf[ni] = *reinterpret_cast<const half8*>(bb + b_off[kk][ni]);
#pragma unroll
                for (int mi = 0; mi < 4; ++mi)
#pragma unroll
                    for (int ni = 0; ni < 4; ++ni)
                        acc[mi][ni] = __builtin_amdgcn_mfma_f32_16x16x32_f16(
                            af[mi], bf[ni], acc[mi][ni], 0, 0, 0);
            }
        }
        __builtin_amdgcn_sched_barrier(0);

        // late half of B staging: wait only B's 4 loads (A glds stay in flight)
        if (j + 1 < ITERS) {
            asm volatile("s_waitcnt vmcnt(4)" ::: "memory");
            writeB(j + 1);
        }
        __syncthreads();   // drains vmcnt(0)+lgkmcnt(0): A glds + B writes done

        // nt epilogue: dump 256x128 in 4 col-slabs of 32, scan into top-6
        if ((j & 7) == 7) {
            const int col0g = chunk * NR + (j >> 3) * BN;
#pragma unroll
            for (int s = 0; s < 4; ++s) {
                if (wn == (s >> 1)) {
                    const int nbase = (s & 1) * 2;
#pragma unroll
                    for (int nn = 0; nn < 2; ++nn)
#pragma unroll
                        for (int mi = 0; mi < 4; ++mi)
#pragma unroll
                            for (int r = 0; r < 4; ++r) {
                                const int row = wm * 64 + mi * 16 + (lane >> 4) * 4 + r;
                                const int cc  = nn * 16 + (lane & 15);
                                Cs[row * CS_STRIDE + cc] = acc[mi][nbase + nn][r];
                            }
                }
                __syncthreads();
                if (tid < 256) {
                    const int base = col0g + s * 32;
                    for (int c = 0; c < 32; ++c) {
                        const float v = Cs[tid * CS_STRIDE + c];
                        const int id = base + c;
                        if (v > topv[CAND - 1] ||
                            (v == topv[CAND - 1] && id < topi[CAND - 1])) {
                            topv[CAND - 1] = v; topi[CAND - 1] = id;
#pragma unroll
                            for (int t = CAND - 1; t > 0; --t) {
                                const bool gt = topv[t] > topv[t - 1] ||
                                    (topv[t] == topv[t - 1] && topi[t] < topi[t - 1]);
                                if (gt) {
                                    const float tv = topv[t]; topv[t] = topv[t - 1]; topv[t - 1] = tv;
                                    const int   ti = topi[t]; topi[t] = topi[t - 1]; topi[t - 1] = ti;
                                }
                            }
                        }
                    }
                }
                __syncthreads();
            }
#pragma unroll
            for (int mi = 0; mi < 4; ++mi)
#pragma unroll
                for (int ni = 0; ni < 4; ++ni) acc[mi][ni] = (f32x4)0.0f;
        }
    }

    if (tid < 256) {
        const size_t base = ((size_t)(row0 + tid) * CHUNKS + chunk) * CAND;
#pragma unroll
        for (int j = 0; j < CAND; ++j) {
            cand_v[base + j] = topv[j];
            cand_i[base + j] = topi[j];
        }
    }
}

// --------------------------------------------------------------------- p2 --
// One block per row. Pivot = 24th-largest chunk-head under (v desc, idx asc)
// => pool {e >= pivot} provably contains the f16-top-24 => true top-10.
// Exact fp32 rescore of the pool from original Q,X; deterministic rank.
__global__ __launch_bounds__(256)
void faiss_p2(const float* __restrict__ cand_v, const int* __restrict__ cand_i,
              const float* __restrict__ Q, const float* __restrict__ X,
              int* __restrict__ out)
{
    __shared__ float vs[NCAND];
    __shared__ int   is[NCAND];
    __shared__ float qs[D_DIM];
    __shared__ int   Sidx[NCAND];
    __shared__ float Sval[NCAND];
    __shared__ int   scount;
    __shared__ float pivV;
    __shared__ int   pivI;

    const int row = blockIdx.x, tid = threadIdx.x;

    for (int i = tid; i < NCAND; i += 256) {
        vs[i] = cand_v[(size_t)row * NCAND + i];
        is[i] = cand_i[(size_t)row * NCAND + i];
    }
    if (tid < 128)
        ((float4*)qs)[tid] = ((const float4*)(Q + (size_t)row * D_DIM))[tid];
    if (tid == 0) scount = 0;
    __syncthreads();

    // rank the 256 chunk-heads; thread with rank 23 publishes the pivot
    {
        const float h = vs[tid * CAND];
        const int  hid = is[tid * CAND];
        int r = 0;
        for (int j = 0; j < CHUNKS; ++j) {
            const float vj = vs[j * CAND];
            r += (vj > h) || (vj == h && is[j * CAND] < hid);
        }
        if (r == 23) { pivV = h; pivI = hid; }
    }
    __syncthreads();

    // filter: keep everything >= pivot under the total order
    const float pv = pivV; const int pi = pivI;
    for (int i = tid; i < NCAND; i += 256) {
        const float v = vs[i]; const int id = is[i];
        if (v > pv || (v == pv && id <= pi)) {
            const int p = atomicAdd(&scount, 1);
            Sidx[p] = id;
        }
    }
    __syncthreads();
    const int nS = scount;

    // exact fp32 rescore: one wave per candidate, deterministic reduce
    const int wv = tid >> 6, ln = tid & 63;
    for (int si = wv; si < nS; si += 4) {
        const float* xr = X + (size_t)Sidx[si] * D_DIM + ln * 8;
        const float4 xa = *(const float4*)(xr);
        const float4 xb = *(const float4*)(xr + 4);
        const float* qp = qs + ln * 8;
        float s = 0.0f;
        s = fmaf(qp[0], xa.x, s); s = fmaf(qp[1], xa.y, s);
        s = fmaf(qp[2], xa.z, s); s = fmaf(qp[3], xa.w, s);
        s = fmaf(qp[4], xb.x, s); s = fmaf(qp[5], xb.y, s);
        s = fmaf(qp[6], xb.z, s); s = fmaf(qp[7], xb.w, s);
#pragma unroll
        for (int off = 32; off > 0; off >>= 1)
            s += __shfl_down(s, off);
        if (ln == 0) Sval[si] = s;
    }
    __syncthreads();

    // final deterministic rank-select among the pool
    for (int i = tid; i < nS; i += 256) {
        const float v = Sval[i]; const int id = Sidx[i];
        int r = 0;
        for (int j = 0; j < nS; ++j) {
            const float vj = Sval[j];
            r += (vj > v) || (vj == v && Sidx[j] < id);
        }
        if (r < TOPK) out[row * TOPK + r] = id;
    }
}

// ----------------------------------------------------------------- launch --
extern "C" void kernel_launch(void* const* d_in, const int* in_sizes, int n_in,
                              void* d_out, int out_size, void* d_ws, size_t ws_size,
                              hipStream_t stream)
{
    (void)in_sizes; (void)n_in; (void)out_size; (void)ws_size;
    const float* Q = (const float*)d_in[0];
    const float* X = (const float*)d_in[1];
    int* out = (int*)d_out;

    char* ws = (char*)d_ws;
    float* cand_v = (float*)ws;                                  // 3.15 MB
    int*   cand_i = (int*)(ws + (size_t)B_Q * NCAND * 4);        // 3.15 MB
    uint4* QswU4  = (uint4*)(ws + (size_t)B_Q * NCAND * 8);      // 512 KB

    qprep<<<dim3(128), dim3(256), 0, stream>>>(Q, QswU4);
    faiss_p1<<<dim3(512), dim3(512), 0, stream>>>(QswU4, X, cand_v, cand_i);
    faiss_p2<<<dim3(B_Q), dim3(256), 0, stream>>>(cand_v, cand_i, Q, X, out);
}